// Round 2
// baseline (336.617 us; speedup 1.0000x reference)
//
#include <hip/hip_runtime.h>
#include <hip/hip_bf16.h>

// Problem constants
#define NB   4
#define CIN  128
#define HH   96
#define WW   96
#define HWN  (HH*WW)        // 9216
#define NHW  (NB*HWN)       // 36864
#define COUT 128
#define KW   9
#define KDIM (CIN*KW)       // 1152
#define GRPS 8
#define GSZ  (COUT/GRPS)    // 16

// ws layout (floats)
#define OFF_WT    0          // 147456: wT[k][c][o]
#define OFF_DX    147456     // 36864
#define OFF_DY    184320     // 36864
#define OFF_MASK  221184     // 36864
#define OFF_GN    258048     // 128: s1[64], s2[64]
#define OFF_STATS 258176     // 64: mu[32], inv[32]

// ---------------------------------------------------------------- zero GN buf
__global__ void zero_gn(float* __restrict__ gn_part) {
    int t = threadIdx.x;
    if (t < 128) gn_part[t] = 0.f;
}

// ---------------------------------------------------------------- transpose
__global__ __launch_bounds__(256) void transpose_w(const float* __restrict__ wd,
                                                   float* __restrict__ wT) {
    int i = blockIdx.x * 256 + threadIdx.x;      // < 147456
    int o = i & 127;
    int rest = i >> 7;                            // k*128 + c
    int c = rest & 127;
    int k = rest >> 7;
    wT[i] = wd[o * KDIM + c * KW + k];
}

// ---------------------------------------------------------------- head conv
__global__ __launch_bounds__(256) void head_kernel(const float* __restrict__ x,
                                                   const float* __restrict__ w_head,
                                                   const float* __restrict__ b_head,
                                                   float* __restrict__ dxv,
                                                   float* __restrict__ dyv,
                                                   float* __restrict__ maskv) {
    __shared__ float wl[3456];    // wl[(c*9+kk)*3 + j]
    int t = threadIdx.x;
    for (int i = t; i < 3456; i += 256) {
        int j = i / KDIM, r = i - j * KDIM;       // r = c*9+kk
        wl[r * 3 + j] = w_head[i];
    }
    __syncthreads();

    int p = blockIdx.x * 256 + t;                 // < 36864 (grid exact)
    int n = p / HWN, hw = p % HWN;
    int h = hw / WW, w = hw % WW;

    int   offs[9];
    float msk[9];
#pragma unroll
    for (int ky = 0; ky < 3; ky++)
#pragma unroll
        for (int kx = 0; kx < 3; kx++) {
            int yy = h - 1 + ky, xx = w - 1 + kx;
            bool ok = (yy >= 0) && (yy < HH) && (xx >= 0) && (xx < WW);
            int yc = min(max(yy, 0), HH - 1), xc = min(max(xx, 0), WW - 1);
            offs[ky * 3 + kx] = yc * WW + xc;
            msk[ky * 3 + kx] = ok ? 1.f : 0.f;
        }

    float a0 = b_head[0], a1 = b_head[1], a2 = b_head[2];
    const float* xn = x + (size_t)n * CIN * HWN;
    for (int c = 0; c < CIN; c++) {
        const float* xc = xn + c * HWN;
        const float* wc = &wl[c * 27];
#pragma unroll
        for (int kk = 0; kk < 9; kk++) {
            float v = xc[offs[kk]] * msk[kk];
            a0 = fmaf(v, wc[kk * 3 + 0], a0);
            a1 = fmaf(v, wc[kk * 3 + 1], a1);
            a2 = fmaf(v, wc[kk * 3 + 2], a2);
        }
    }
    dxv[p]   = 0.25f * tanhf(a0);
    dyv[p]   = 0.25f * tanhf(a1);
    maskv[p] = 1.f / (1.f + expf(-a2));
}

// ---------------------------------------------------------------- main DCN
// Block: 128 out-channels x 64 pixels. 256 threads: thread -> (ow=t&31 -> o0=4*ow,
// pg=t>>5 -> pixels pg*8..pg*8+7). K loop: 9 taps x 4 chunks of 32 channels.
__global__ __launch_bounds__(256) void dcn_kernel(const float* __restrict__ x,
                                                  const float* __restrict__ wT,
                                                  const float* __restrict__ dxv,
                                                  const float* __restrict__ dyv,
                                                  const float* __restrict__ maskv,
                                                  float* __restrict__ out,
                                                  float* __restrict__ gn_part) {
    __shared__ float sW[32 * 128];     // [c][o] 16 KB
    __shared__ float sS[32 * 64];      // [c][pix] 8 KB
    __shared__ int   sAddr[64 * 4];
    __shared__ float sWgt[64 * 4];
    __shared__ float sDx[64], sDy[64], sMask[64];
    __shared__ float gred[16];         // 8 groups x {s1,s2}

    const int t  = threadIdx.x;
    const int p0 = blockIdx.x * 64;
    const int n  = p0 / HWN;
    const int hw0 = p0 % HWN;
    const float* xn = x + (size_t)n * CIN * HWN;

    if (t < 64) { sDx[t] = dxv[p0 + t]; sDy[t] = dyv[p0 + t]; sMask[t] = maskv[p0 + t]; }
    if (t < 16) gred[t] = 0.f;

    float acc[4][8];
#pragma unroll
    for (int i = 0; i < 4; i++)
#pragma unroll
        for (int j = 0; j < 8; j++) acc[i][j] = 0.f;

    const int ow = t & 31, pg = t >> 5;
    const int o0 = ow * 4;

    // per-tap offset multipliers: oy = oyc[k]*dx, ox = oxc[k]*dy
    const int oyc[9] = {0, 0, 0, 1, 0, -1, 1, 1, -1};
    const int oxc[9] = {0, 1, -1, 0, 0, 0, 1, -1, 1};

    for (int k = 0; k < 9; ++k) {
        __syncthreads();   // protect sAddr/sWgt (and gred/sDx init for k=0)
        if (t < 64) {
            int hw = hw0 + t;
            int h = hw / WW, w = hw % WW;
            int ky = k / 3, kx = k - ky * 3;
            float py = (float)(h - 1 + ky) + (float)oyc[k] * sDx[t];
            float px = (float)(w - 1 + kx) + (float)oxc[k] * sDy[t];
            float fy0 = floorf(py), fx0 = floorf(px);
            int y0 = (int)fy0, x0 = (int)fx0;
            float fy = py - fy0, fx = px - fx0;
#pragma unroll
            for (int j = 0; j < 4; ++j) {
                int yy = y0 + (j >> 1), xx = x0 + (j & 1);
                float wb = ((j >> 1) ? fy : 1.f - fy) * ((j & 1) ? fx : 1.f - fx);
                bool ok = (yy >= 0) && (yy < HH) && (xx >= 0) && (xx < WW);
                int yc = min(max(yy, 0), HH - 1), xc = min(max(xx, 0), WW - 1);
                sAddr[t * 4 + j] = yc * WW + xc;
                sWgt[t * 4 + j] = ok ? wb : 0.f;
            }
        }
        __syncthreads();

        for (int cc = 0; cc < CIN; cc += 32) {
            // stage W tile: 4096 floats, coalesced float4
            const float4* wsrc = (const float4*)(wT + ((k * CIN + cc) << 7));
            float4* wdst = (float4*)sW;
#pragma unroll
            for (int i = 0; i < 4; i++) wdst[t + (i << 8)] = wsrc[t + (i << 8)];
            // stage S tile: 2048 sampled values (4 gathers each)
#pragma unroll
            for (int i = 0; i < 8; i++) {
                int idx = t + (i << 8);                 // 0..2047
                int c = idx >> 6, pix = idx & 63;
                const float* xc = xn + (size_t)(cc + c) * HWN;
                float s = xc[sAddr[pix * 4 + 0]] * sWgt[pix * 4 + 0]
                        + xc[sAddr[pix * 4 + 1]] * sWgt[pix * 4 + 1]
                        + xc[sAddr[pix * 4 + 2]] * sWgt[pix * 4 + 2]
                        + xc[sAddr[pix * 4 + 3]] * sWgt[pix * 4 + 3];
                sS[c * 64 + pix] = s;
            }
            __syncthreads();
#pragma unroll
            for (int c = 0; c < 32; ++c) {
                float4 a  = *(const float4*)&sW[c * 128 + o0];
                float4 b0 = *(const float4*)&sS[c * 64 + pg * 8];
                float4 b1 = *(const float4*)&sS[c * 64 + pg * 8 + 4];
                float av[4] = {a.x, a.y, a.z, a.w};
                float bv[8] = {b0.x, b0.y, b0.z, b0.w, b1.x, b1.y, b1.z, b1.w};
#pragma unroll
                for (int i = 0; i < 4; i++)
#pragma unroll
                    for (int j = 0; j < 8; j++) acc[i][j] = fmaf(av[i], bv[j], acc[i][j]);
            }
            __syncthreads();
        }
    }

    // epilogue: mask multiply, store pre-GN y, GN partial sums
    float m[8];
#pragma unroll
    for (int j = 0; j < 8; j++) m[j] = sMask[pg * 8 + j];
    float s1 = 0.f, s2 = 0.f;
#pragma unroll
    for (int i = 0; i < 4; i++) {
        float v[8];
#pragma unroll
        for (int j = 0; j < 8; j++) {
            v[j] = acc[i][j] * m[j];
            s1 += v[j];
            s2 += v[j] * v[j];
        }
        float* dst = out + ((size_t)(n * COUT) + (o0 + i)) * HWN + hw0 + pg * 8;
        *(float4*)dst       = make_float4(v[0], v[1], v[2], v[3]);
        *(float4*)(dst + 4) = make_float4(v[4], v[5], v[6], v[7]);
    }
    int g = o0 >> 4;
    atomicAdd(&gred[g * 2 + 0], s1);
    atomicAdd(&gred[g * 2 + 1], s2);
    __syncthreads();
    if (t < 8) {
        atomicAdd(&gn_part[n * 8 + t], gred[t * 2 + 0]);
        atomicAdd(&gn_part[64 + n * 8 + t], gred[t * 2 + 1]);
    }
}

// ---------------------------------------------------------------- GN stats
__global__ void gn_stats(const float* __restrict__ gn_part, float* __restrict__ stats) {
    int i = threadIdx.x;
    if (i < 32) {
        float cnt = (float)GSZ * (float)HWN;
        float s1 = gn_part[i], s2 = gn_part[64 + i];
        float mu = s1 / cnt;
        float var = s2 / cnt - mu * mu;
        stats[i] = mu;
        stats[32 + i] = rsqrtf(var + 1e-5f);
    }
}

// ---------------------------------------------------------------- GN apply
__global__ __launch_bounds__(256) void gn_apply(float* __restrict__ out,
                                                const float* __restrict__ stats,
                                                const float* __restrict__ gamma,
                                                const float* __restrict__ beta) {
    int i4 = blockIdx.x * 256 + threadIdx.x;      // < 1179648
    size_t e = (size_t)i4 * 4;
    int og = (int)(e / HWN);                      // n*128 + o
    int n = og >> 7, o = og & 127;
    int s = n * 8 + (o >> 4);
    float mu = stats[s], inv = stats[32 + s];
    float ga = gamma[o] * inv;
    float be = beta[o] - mu * ga;
    float4 v = *(float4*)(out + e);
    v.x = fmaxf(fmaf(v.x, ga, be), 0.f);
    v.y = fmaxf(fmaf(v.y, ga, be), 0.f);
    v.z = fmaxf(fmaf(v.z, ga, be), 0.f);
    v.w = fmaxf(fmaf(v.w, ga, be), 0.f);
    *(float4*)(out + e) = v;
}

// ---------------------------------------------------------------- launch
extern "C" void kernel_launch(void* const* d_in, const int* in_sizes, int n_in,
                              void* d_out, int out_size, void* d_ws, size_t ws_size,
                              hipStream_t stream) {
    const float* x       = (const float*)d_in[0];
    const float* w_head  = (const float*)d_in[1];
    const float* b_head  = (const float*)d_in[2];
    const float* w_dcn   = (const float*)d_in[3];
    const float* gamma   = (const float*)d_in[4];
    const float* beta    = (const float*)d_in[5];
    float* out = (float*)d_out;
    float* ws  = (float*)d_ws;

    float* wT      = ws + OFF_WT;
    float* dxv     = ws + OFF_DX;
    float* dyv     = ws + OFF_DY;
    float* maskv   = ws + OFF_MASK;
    float* gn_part = ws + OFF_GN;
    float* stats   = ws + OFF_STATS;

    zero_gn<<<1, 128, 0, stream>>>(gn_part);
    transpose_w<<<147456 / 256, 256, 0, stream>>>(w_dcn, wT);
    head_kernel<<<NHW / 256, 256, 0, stream>>>(x, w_head, b_head, dxv, dyv, maskv);
    dcn_kernel<<<NHW / 64, 256, 0, stream>>>(x, wT, dxv, dyv, maskv, out, gn_part);
    gn_stats<<<1, 64, 0, stream>>>(gn_part, stats);
    gn_apply<<<(NB * COUT * HWN) / 4 / 256, 256, 0, stream>>>(out, stats, gamma, beta);
}